// Round 1
// baseline (222.896 us; speedup 1.0000x reference)
//
#include <hip/hip_runtime.h>
#include <hip/hip_bf16.h>
#include <math.h>

#define N_TRACK 50000
#define N_LANE  50000
#define N_ATT   (N_TRACK + N_LANE)
#define NP_T    1000000
#define NP_L    500000
#define E_ATT   1600000
#define HEADS   30
#define EPS     1e-5f
#define NEG_SLOPE 0.2f

// ---------------- Track point MLP + segment max ----------------
__global__ void track_point_kernel(const float4* __restrict__ x, const int* __restrict__ ids,
                                   const float* __restrict__ W, const float* __restrict__ b,
                                   const float* __restrict__ g, const float* __restrict__ beta,
                                   float* __restrict__ pool, int np) {
    int tid = blockIdx.x * blockDim.x + threadIdx.x;
    int lane = threadIdx.x & 63;
    int id = -1;
    float y[4] = {0.f, 0.f, 0.f, 0.f};
    if (tid < np) {
        float4 xv = x[tid];
        float h[4];
        #pragma unroll
        for (int j = 0; j < 4; j++)
            h[j] = xv.x * W[0*4+j] + xv.y * W[1*4+j] + xv.z * W[2*4+j] + xv.w * W[3*4+j] + b[j];
        float mu = 0.25f * (h[0] + h[1] + h[2] + h[3]);
        float var = 0.f;
        #pragma unroll
        for (int j = 0; j < 4; j++) { float d = h[j] - mu; var += d * d; }
        var *= 0.25f;
        float r = rsqrtf(var + EPS);
        #pragma unroll
        for (int j = 0; j < 4; j++)
            y[j] = fmaxf((h[j] - mu) * r * g[j] + beta[j], 0.f);
        id = ids[tid];
    }
    // wave-level segmented max scan (ids sorted; wrap-around merge is same-segment-safe)
    #pragma unroll
    for (int d = 1; d < 64; d <<= 1) {
        int oid = __shfl_down(id, d, 64);
        float o0 = __shfl_down(y[0], d, 64);
        float o1 = __shfl_down(y[1], d, 64);
        float o2 = __shfl_down(y[2], d, 64);
        float o3 = __shfl_down(y[3], d, 64);
        if (oid == id) {
            y[0] = fmaxf(y[0], o0); y[1] = fmaxf(y[1], o1);
            y[2] = fmaxf(y[2], o2); y[3] = fmaxf(y[3], o3);
        }
    }
    int pid = __shfl_up(id, 1, 64);
    bool head = (lane == 0) || (pid != id);
    if (id >= 0 && head) {
        #pragma unroll
        for (int j = 0; j < 4; j++)
            atomicMax((unsigned int*)&pool[(size_t)id * 4 + j], __float_as_uint(y[j]));
    }
}

// ---------------- Lane point MLP + segment max ----------------
__global__ void lane_point_kernel(const float2* __restrict__ x, const int* __restrict__ ids,
                                  const float* __restrict__ W, const float* __restrict__ b,
                                  const float* __restrict__ g, const float* __restrict__ beta,
                                  float* __restrict__ pool, int np) {
    int tid = blockIdx.x * blockDim.x + threadIdx.x;
    int lane = threadIdx.x & 63;
    int id = -1;
    float y[2] = {0.f, 0.f};
    if (tid < np) {
        float2 xv = x[tid];
        float h[2];
        #pragma unroll
        for (int j = 0; j < 2; j++)
            h[j] = xv.x * W[0*2+j] + xv.y * W[1*2+j] + b[j];
        float mu = 0.5f * (h[0] + h[1]);
        float var = 0.5f * ((h[0]-mu)*(h[0]-mu) + (h[1]-mu)*(h[1]-mu));
        float r = rsqrtf(var + EPS);
        #pragma unroll
        for (int j = 0; j < 2; j++)
            y[j] = fmaxf((h[j] - mu) * r * g[j] + beta[j], 0.f);
        id = ids[tid];
    }
    #pragma unroll
    for (int d = 1; d < 64; d <<= 1) {
        int oid = __shfl_down(id, d, 64);
        float o0 = __shfl_down(y[0], d, 64);
        float o1 = __shfl_down(y[1], d, 64);
        if (oid == id) {
            y[0] = fmaxf(y[0], o0); y[1] = fmaxf(y[1], o1);
        }
    }
    int pid = __shfl_up(id, 1, 64);
    bool head = (lane == 0) || (pid != id);
    if (id >= 0 && head) {
        #pragma unroll
        for (int j = 0; j < 2; j++)
            atomicMax((unsigned int*)&pool[(size_t)id * 2 + j], __float_as_uint(y[j]));
    }
}

// ---------------- Node stage: pool -> feats(10) -> h(60), el(30) ----------------
__global__ void node_kernel(const float* __restrict__ pool_t, const float* __restrict__ pool_l,
                            const float* __restrict__ tW, const float* __restrict__ tb,
                            const float* __restrict__ lW, const float* __restrict__ lb,
                            const float* __restrict__ fcW, const float* __restrict__ attn_l,
                            float* __restrict__ h_arr, float* __restrict__ el_arr) {
    __shared__ float s_fc[600];
    __shared__ float s_tW[40], s_tb[10], s_lW[20], s_lb[10], s_al[60];
    for (int t = threadIdx.x; t < 600; t += blockDim.x) s_fc[t] = fcW[t];
    for (int t = threadIdx.x; t < 40; t += blockDim.x) s_tW[t] = tW[t];
    for (int t = threadIdx.x; t < 10; t += blockDim.x) s_tb[t] = tb[t];
    for (int t = threadIdx.x; t < 20; t += blockDim.x) s_lW[t] = lW[t];
    for (int t = threadIdx.x; t < 10; t += blockDim.x) s_lb[t] = lb[t];
    for (int t = threadIdx.x; t < 60; t += blockDim.x) s_al[t] = attn_l[t];
    __syncthreads();

    int i = blockIdx.x * blockDim.x + threadIdx.x;
    if (i >= N_ATT) return;

    float f[10];
    if (i < N_TRACK) {
        const float* p = pool_t + (size_t)i * 4;
        float p0 = p[0], p1 = p[1], p2 = p[2], p3 = p[3];
        #pragma unroll
        for (int j = 0; j < 10; j++)
            f[j] = p0 * s_tW[0*10+j] + p1 * s_tW[1*10+j] + p2 * s_tW[2*10+j] + p3 * s_tW[3*10+j] + s_tb[j];
    } else {
        const float* p = pool_l + (size_t)(i - N_TRACK) * 2;
        float p0 = p[0], p1 = p[1];
        #pragma unroll
        for (int j = 0; j < 10; j++)
            f[j] = p0 * s_lW[0*10+j] + p1 * s_lW[1*10+j] + s_lb[j];
    }

    float h[60];
    #pragma unroll
    for (int c = 0; c < 60; c++) {
        float acc = 0.f;
        #pragma unroll
        for (int k = 0; k < 10; k++) acc += f[k] * s_fc[k*60 + c];
        h[c] = acc;
    }

    float4* hp = (float4*)(h_arr + (size_t)i * 60);
    #pragma unroll
    for (int q = 0; q < 15; q++)
        hp[q] = make_float4(h[4*q], h[4*q+1], h[4*q+2], h[4*q+3]);

    float el[30];
    #pragma unroll
    for (int hh = 0; hh < 30; hh++)
        el[hh] = h[2*hh] * s_al[2*hh] + h[2*hh+1] * s_al[2*hh+1];
    float2* ep = (float2*)(el_arr + (size_t)i * 30);
    #pragma unroll
    for (int q = 0; q < 15; q++)
        ep[q] = make_float2(el[2*q], el[2*q+1]);
}

// ---------------- Per-dst edge offsets (att_dst sorted) ----------------
__global__ void off_kernel(const int* __restrict__ dst, int* __restrict__ off) {
    int i = blockIdx.x * blockDim.x + threadIdx.x;
    if (i > N_TRACK) return;
    int lo = 0, hi = E_ATT;
    while (lo < hi) {
        int mid = (lo + hi) >> 1;
        if (dst[mid] < i) lo = mid + 1; else hi = mid;
    }
    off[i] = lo;
}

// ---------------- Edge softmax + aggregate: 32 lanes per dst, lane = head ----------------
__global__ void edge_kernel(const int* __restrict__ src, const int* __restrict__ off,
                            const float* __restrict__ h_arr, const float* __restrict__ el_arr,
                            const float* __restrict__ attn_r, const float* __restrict__ bias,
                            float* __restrict__ out) {
    int grp = blockIdx.x * 8 + (threadIdx.x >> 5);
    int hh = threadIdx.x & 31;
    if (grp >= N_TRACK || hh >= HEADS) return;

    float ar0 = attn_r[2*hh], ar1 = attn_r[2*hh+1];
    const float2* hvec = (const float2*)h_arr;
    float2 hd = hvec[(size_t)grp * 30 + hh];
    float er = hd.x * ar0 + hd.y * ar1;

    int s = off[grp], e = off[grp + 1];
    float m = -INFINITY, den = 0.f, n0 = 0.f, n1 = 0.f;
    for (int k = s; k < e; k++) {
        int sv = src[k];
        float ev = el_arr[(size_t)sv * 30 + hh] + er;
        ev = (ev > 0.f) ? ev : NEG_SLOPE * ev;
        float nm = fmaxf(m, ev);
        float scale = __expf(m - nm);     // first iter: exp(-inf)=0
        float w = __expf(ev - nm);
        float2 hs = hvec[(size_t)sv * 30 + hh];
        den = den * scale + w;
        n0 = n0 * scale + w * hs.x;
        n1 = n1 * scale + w * hs.y;
        m = nm;
    }
    float o0 = 0.f, o1 = 0.f;
    if (den > 0.f) {
        float inv = 1.f / den;
        o0 = n0 * inv; o1 = n1 * inv;
    }
    out[(size_t)grp * 60 + 2*hh]     = o0 + bias[2*hh];
    out[(size_t)grp * 60 + 2*hh + 1] = o1 + bias[2*hh+1];
}

extern "C" void kernel_launch(void* const* d_in, const int* in_sizes, int n_in,
                              void* d_out, int out_size, void* d_ws, size_t ws_size,
                              hipStream_t stream) {
    const float4* track_pts = (const float4*)d_in[0];
    const float2* lane_pts  = (const float2*)d_in[1];
    const int* pt_track_id  = (const int*)d_in[2];
    const int* pt_lane_id   = (const int*)d_in[3];
    const int* att_src      = (const int*)d_in[4];
    const int* att_dst      = (const int*)d_in[5];
    const float* track_mlp_W = (const float*)d_in[6];
    const float* track_mlp_b = (const float*)d_in[7];
    const float* track_ln_g  = (const float*)d_in[8];
    const float* track_ln_b  = (const float*)d_in[9];
    const float* track_out_W = (const float*)d_in[10];
    const float* track_out_b = (const float*)d_in[11];
    const float* lane_mlp_W  = (const float*)d_in[12];
    const float* lane_mlp_b  = (const float*)d_in[13];
    const float* lane_ln_g   = (const float*)d_in[14];
    const float* lane_ln_b   = (const float*)d_in[15];
    const float* lane_out_W  = (const float*)d_in[16];
    const float* lane_out_b  = (const float*)d_in[17];
    const float* gat_fc_W    = (const float*)d_in[18];
    const float* gat_attn_l  = (const float*)d_in[19];
    const float* gat_attn_r  = (const float*)d_in[20];
    const float* gat_bias    = (const float*)d_in[21];
    float* out = (float*)d_out;

    // workspace layout
    float* pool_t = (float*)d_ws;                 // 50000*4
    float* pool_l = pool_t + 200000;              // 50000*2
    float* h_arr  = pool_l + 100000;              // 100000*60
    float* el_arr = h_arr + 6000000;              // 100000*30
    int*   off    = (int*)(el_arr + 3000000);     // N_TRACK+1

    // zero the pools (ReLU outputs >= 0, empty segments -> 0)
    hipMemsetAsync(d_ws, 0, 300000 * sizeof(float), stream);

    track_point_kernel<<<(NP_T + 255) / 256, 256, 0, stream>>>(
        track_pts, pt_track_id, track_mlp_W, track_mlp_b, track_ln_g, track_ln_b, pool_t, NP_T);
    lane_point_kernel<<<(NP_L + 255) / 256, 256, 0, stream>>>(
        lane_pts, pt_lane_id, lane_mlp_W, lane_mlp_b, lane_ln_g, lane_ln_b, pool_l, NP_L);
    node_kernel<<<(N_ATT + 255) / 256, 256, 0, stream>>>(
        pool_t, pool_l, track_out_W, track_out_b, lane_out_W, lane_out_b,
        gat_fc_W, gat_attn_l, h_arr, el_arr);
    off_kernel<<<(N_TRACK + 1 + 255) / 256, 256, 0, stream>>>(att_dst, off);
    edge_kernel<<<(N_TRACK + 7) / 8, 256, 0, stream>>>(
        att_src, off, h_arr, el_arr, gat_attn_r, gat_bias, out);
}

// Round 2
// 209.229 us; speedup vs baseline: 1.0653x; 1.0653x over previous
//
#include <hip/hip_runtime.h>
#include <hip/hip_bf16.h>
#include <math.h>

#define N_TRACK 50000
#define N_LANE  50000
#define N_ATT   (N_TRACK + N_LANE)
#define NP_T    1000000
#define NP_L    500000
#define E_ATT   1600000
#define HEADS   30
#define EPS     1e-5f
#define NEG_SLOPE 0.2f

// Packed per-node record: 30 heads x [el, h0, h1] (3 floats), padded to 96 floats
// (384 B = exactly 3 cache lines, 16B-aligned for float4 stores).
#define REC_STRIDE 96

// ---------------- Merged point MLP + segment max (track + lane) ----------------
// Disjoint id encoding (track: [0,50K), lane: [50K,100K)) keeps the wave-level
// segmented scan correct even in the wave straddling the track/lane boundary.
__global__ void point_kernel(const float4* __restrict__ xt, const float2* __restrict__ xl,
                             const int* __restrict__ idt, const int* __restrict__ idl,
                             const float* __restrict__ tW, const float* __restrict__ tb,
                             const float* __restrict__ tg, const float* __restrict__ tbeta,
                             const float* __restrict__ lW, const float* __restrict__ lb,
                             const float* __restrict__ lg, const float* __restrict__ lbeta,
                             float* __restrict__ pool_t, float* __restrict__ pool_l) {
    int tid = blockIdx.x * blockDim.x + threadIdx.x;
    int lane = threadIdx.x & 63;
    int id = -1;
    float y0 = 0.f, y1 = 0.f, y2 = 0.f, y3 = 0.f;
    if (tid < NP_T) {
        float4 xv = xt[tid];
        float h[4];
        #pragma unroll
        for (int j = 0; j < 4; j++)
            h[j] = xv.x * tW[0*4+j] + xv.y * tW[1*4+j] + xv.z * tW[2*4+j] + xv.w * tW[3*4+j] + tb[j];
        float mu = 0.25f * (h[0] + h[1] + h[2] + h[3]);
        float var = 0.f;
        #pragma unroll
        for (int j = 0; j < 4; j++) { float d = h[j] - mu; var += d * d; }
        var *= 0.25f;
        float r = rsqrtf(var + EPS);
        y0 = fmaxf((h[0] - mu) * r * tg[0] + tbeta[0], 0.f);
        y1 = fmaxf((h[1] - mu) * r * tg[1] + tbeta[1], 0.f);
        y2 = fmaxf((h[2] - mu) * r * tg[2] + tbeta[2], 0.f);
        y3 = fmaxf((h[3] - mu) * r * tg[3] + tbeta[3], 0.f);
        id = idt[tid];
    } else if (tid < NP_T + NP_L) {
        int t = tid - NP_T;
        float2 xv = xl[t];
        float h0 = xv.x * lW[0] + xv.y * lW[2] + lb[0];
        float h1 = xv.x * lW[1] + xv.y * lW[3] + lb[1];
        float mu = 0.5f * (h0 + h1);
        float var = 0.5f * ((h0 - mu) * (h0 - mu) + (h1 - mu) * (h1 - mu));
        float r = rsqrtf(var + EPS);
        y0 = fmaxf((h0 - mu) * r * lg[0] + lbeta[0], 0.f);
        y1 = fmaxf((h1 - mu) * r * lg[1] + lbeta[1], 0.f);
        id = N_TRACK + idl[t];
    }
    // wave-level segmented max scan (ids sorted within each domain; encodings disjoint)
    #pragma unroll
    for (int d = 1; d < 64; d <<= 1) {
        int oid = __shfl_down(id, d, 64);
        float o0 = __shfl_down(y0, d, 64);
        float o1 = __shfl_down(y1, d, 64);
        float o2 = __shfl_down(y2, d, 64);
        float o3 = __shfl_down(y3, d, 64);
        if (oid == id) {
            y0 = fmaxf(y0, o0); y1 = fmaxf(y1, o1);
            y2 = fmaxf(y2, o2); y3 = fmaxf(y3, o3);
        }
    }
    int pid = __shfl_up(id, 1, 64);
    bool head = (lane == 0) || (pid != id);
    if (id >= 0 && head) {
        if (id < N_TRACK) {
            unsigned int* p = (unsigned int*)&pool_t[(size_t)id * 4];
            atomicMax(p + 0, __float_as_uint(y0));
            atomicMax(p + 1, __float_as_uint(y1));
            atomicMax(p + 2, __float_as_uint(y2));
            atomicMax(p + 3, __float_as_uint(y3));
        } else {
            unsigned int* p = (unsigned int*)&pool_l[(size_t)(id - N_TRACK) * 2];
            atomicMax(p + 0, __float_as_uint(y0));
            atomicMax(p + 1, __float_as_uint(y1));
        }
    }
}

// ---------------- Node stage: pool -> feats(10) -> packed [el,h0,h1]x30; fused off[] ----------------
__global__ void node_kernel(const float* __restrict__ pool_t, const float* __restrict__ pool_l,
                            const float* __restrict__ tW, const float* __restrict__ tb,
                            const float* __restrict__ lW, const float* __restrict__ lb,
                            const float* __restrict__ fcW, const float* __restrict__ attn_l,
                            const int* __restrict__ att_dst,
                            float* __restrict__ packed, int* __restrict__ off) {
    int i = blockIdx.x * blockDim.x + threadIdx.x;

    // fused per-dst edge offsets (att_dst sorted): threads 0..N_TRACK
    if (i <= N_TRACK) {
        int lo = 0, hi = E_ATT;
        while (lo < hi) {
            int mid = (lo + hi) >> 1;
            if (att_dst[mid] < i) lo = mid + 1; else hi = mid;
        }
        off[i] = lo;
    }
    if (i >= N_ATT) return;

    float f[10];
    if (i < N_TRACK) {
        const float4 p = *(const float4*)(pool_t + (size_t)i * 4);
        #pragma unroll
        for (int j = 0; j < 10; j++)
            f[j] = p.x * tW[0*10+j] + p.y * tW[1*10+j] + p.z * tW[2*10+j] + p.w * tW[3*10+j] + tb[j];
    } else {
        const float2 p = *(const float2*)(pool_l + (size_t)(i - N_TRACK) * 2);
        #pragma unroll
        for (int j = 0; j < 10; j++)
            f[j] = p.x * lW[0*10+j] + p.y * lW[1*10+j] + lb[j];
    }

    float rec[REC_STRIDE];
    // h columns c=0..59 -> rec[3*(c>>1) + 1 + (c&1)]  (weights are thread-uniform -> scalar loads)
    #pragma unroll
    for (int c = 0; c < 60; c++) {
        float acc = 0.f;
        #pragma unroll
        for (int k = 0; k < 10; k++) acc += f[k] * fcW[k * 60 + c];
        rec[3 * (c >> 1) + 1 + (c & 1)] = acc;
    }
    #pragma unroll
    for (int hh = 0; hh < HEADS; hh++)
        rec[3 * hh] = rec[3 * hh + 1] * attn_l[2 * hh] + rec[3 * hh + 2] * attn_l[2 * hh + 1];
    #pragma unroll
    for (int q = 90; q < 96; q++) rec[q] = 0.f;

    float4* rp = (float4*)(packed + (size_t)i * REC_STRIDE);
    #pragma unroll
    for (int q = 0; q < 24; q++)
        rp[q] = make_float4(rec[4*q], rec[4*q+1], rec[4*q+2], rec[4*q+3]);
}

// ---------------- Edge softmax + aggregate: 32 lanes per dst, lane = head ----------------
__global__ void edge_kernel(const int* __restrict__ src, const int* __restrict__ off,
                            const float* __restrict__ packed,
                            const float* __restrict__ attn_r, const float* __restrict__ bias,
                            float* __restrict__ out) {
    int grp = blockIdx.x * 8 + (threadIdx.x >> 5);
    int hh = threadIdx.x & 31;
    if (grp >= N_TRACK || hh >= HEADS) return;

    const float* prec = packed + (size_t)grp * REC_STRIDE + hh * 3;
    float er = prec[1] * attn_r[2 * hh] + prec[2] * attn_r[2 * hh + 1];

    int s = off[grp], e = off[grp + 1];
    float m = -INFINITY, den = 0.f, n0 = 0.f, n1 = 0.f;

    for (int kk = s; kk < e; kk += 8) {
        int lim = e - kk;  // >= 1; uniform per 32-lane group
        int sv[8];
        #pragma unroll
        for (int j = 0; j < 8; j++) sv[j] = src[kk + (j < lim ? j : 0)];
        float e_[8], a_[8], b_[8];
        #pragma unroll
        for (int j = 0; j < 8; j++) {
            const float* p = packed + (size_t)sv[j] * REC_STRIDE + hh * 3;
            e_[j] = p[0]; a_[j] = p[1]; b_[j] = p[2];
        }
        #pragma unroll
        for (int j = 0; j < 8; j++) {
            if (j < lim) {
                float ev = e_[j] + er;
                ev = (ev > 0.f) ? ev : NEG_SLOPE * ev;
                float nm = fmaxf(m, ev);
                float sc = __expf(m - nm);   // first edge: exp(-inf) = 0
                float w  = __expf(ev - nm);
                den = den * sc + w;
                n0  = n0 * sc + w * a_[j];
                n1  = n1 * sc + w * b_[j];
                m = nm;
            }
        }
    }

    float o0 = 0.f, o1 = 0.f;
    if (den > 0.f) {
        float inv = 1.f / den;
        o0 = n0 * inv; o1 = n1 * inv;
    }
    ((float2*)out)[(size_t)grp * HEADS + hh] =
        make_float2(o0 + bias[2 * hh], o1 + bias[2 * hh + 1]);
}

extern "C" void kernel_launch(void* const* d_in, const int* in_sizes, int n_in,
                              void* d_out, int out_size, void* d_ws, size_t ws_size,
                              hipStream_t stream) {
    const float4* track_pts = (const float4*)d_in[0];
    const float2* lane_pts  = (const float2*)d_in[1];
    const int* pt_track_id  = (const int*)d_in[2];
    const int* pt_lane_id   = (const int*)d_in[3];
    const int* att_src      = (const int*)d_in[4];
    const int* att_dst      = (const int*)d_in[5];
    const float* track_mlp_W = (const float*)d_in[6];
    const float* track_mlp_b = (const float*)d_in[7];
    const float* track_ln_g  = (const float*)d_in[8];
    const float* track_ln_b  = (const float*)d_in[9];
    const float* track_out_W = (const float*)d_in[10];
    const float* track_out_b = (const float*)d_in[11];
    const float* lane_mlp_W  = (const float*)d_in[12];
    const float* lane_mlp_b  = (const float*)d_in[13];
    const float* lane_ln_g   = (const float*)d_in[14];
    const float* lane_ln_b   = (const float*)d_in[15];
    const float* lane_out_W  = (const float*)d_in[16];
    const float* lane_out_b  = (const float*)d_in[17];
    const float* gat_fc_W    = (const float*)d_in[18];
    const float* gat_attn_l  = (const float*)d_in[19];
    const float* gat_attn_r  = (const float*)d_in[20];
    const float* gat_bias    = (const float*)d_in[21];
    float* out = (float*)d_out;

    // workspace layout (all word offsets; packed kept 16B-aligned)
    float* pool_t = (float*)d_ws;                  // 200000 floats
    float* pool_l = pool_t + 200000;               // 100000 floats
    int*   off    = (int*)(pool_l + 100000);       // 50001 ints (pad to 50004)
    float* packed = (float*)(off + 50004);         // 100000 * 96 floats

    // zero the pools (ReLU outputs >= 0, empty segments -> 0)
    hipMemsetAsync(d_ws, 0, 300000 * sizeof(float), stream);

    point_kernel<<<(NP_T + NP_L + 255) / 256, 256, 0, stream>>>(
        track_pts, lane_pts, pt_track_id, pt_lane_id,
        track_mlp_W, track_mlp_b, track_ln_g, track_ln_b,
        lane_mlp_W, lane_mlp_b, lane_ln_g, lane_ln_b,
        pool_t, pool_l);
    node_kernel<<<(N_ATT + 255) / 256, 256, 0, stream>>>(
        pool_t, pool_l, track_out_W, track_out_b, lane_out_W, lane_out_b,
        gat_fc_W, gat_attn_l, att_dst, packed, off);
    edge_kernel<<<(N_TRACK + 7) / 8, 256, 0, stream>>>(
        att_src, off, packed, gat_attn_r, gat_bias, out);
}

// Round 3
// 174.017 us; speedup vs baseline: 1.2809x; 1.2023x over previous
//
#include <hip/hip_runtime.h>
#include <hip/hip_bf16.h>
#include <math.h>

#define N_TRACK 50000
#define N_LANE  50000
#define N_ATT   (N_TRACK + N_LANE)
#define NP_T    1000000
#define NP_L    500000
#define E_ATT   1600000
#define HEADS   30
#define EPS     1e-5f
#define NEG_SLOPE 0.2f

// Packed per-node record: 30 heads x (h0,h1) as bf16 pair in one dword,
// padded to 32 dwords = 128 B = exactly ONE cache line per node.
#define REC_DW 32

// ---------------- Merged point MLP + segment max (track + lane) ----------------
__global__ void point_kernel(const float4* __restrict__ xt, const float2* __restrict__ xl,
                             const int* __restrict__ idt, const int* __restrict__ idl,
                             const float* __restrict__ tW, const float* __restrict__ tb,
                             const float* __restrict__ tg, const float* __restrict__ tbeta,
                             const float* __restrict__ lW, const float* __restrict__ lb,
                             const float* __restrict__ lg, const float* __restrict__ lbeta,
                             float* __restrict__ pool_t, float* __restrict__ pool_l) {
    int tid = blockIdx.x * blockDim.x + threadIdx.x;
    int lane = threadIdx.x & 63;
    int id = -1;
    float y0 = 0.f, y1 = 0.f, y2 = 0.f, y3 = 0.f;
    if (tid < NP_T) {
        float4 xv = xt[tid];
        float h[4];
        #pragma unroll
        for (int j = 0; j < 4; j++)
            h[j] = xv.x * tW[0*4+j] + xv.y * tW[1*4+j] + xv.z * tW[2*4+j] + xv.w * tW[3*4+j] + tb[j];
        float mu = 0.25f * (h[0] + h[1] + h[2] + h[3]);
        float var = 0.f;
        #pragma unroll
        for (int j = 0; j < 4; j++) { float d = h[j] - mu; var += d * d; }
        var *= 0.25f;
        float r = rsqrtf(var + EPS);
        y0 = fmaxf((h[0] - mu) * r * tg[0] + tbeta[0], 0.f);
        y1 = fmaxf((h[1] - mu) * r * tg[1] + tbeta[1], 0.f);
        y2 = fmaxf((h[2] - mu) * r * tg[2] + tbeta[2], 0.f);
        y3 = fmaxf((h[3] - mu) * r * tg[3] + tbeta[3], 0.f);
        id = idt[tid];
    } else if (tid < NP_T + NP_L) {
        int t = tid - NP_T;
        float2 xv = xl[t];
        float h0 = xv.x * lW[0] + xv.y * lW[2] + lb[0];
        float h1 = xv.x * lW[1] + xv.y * lW[3] + lb[1];
        float mu = 0.5f * (h0 + h1);
        float var = 0.5f * ((h0 - mu) * (h0 - mu) + (h1 - mu) * (h1 - mu));
        float r = rsqrtf(var + EPS);
        y0 = fmaxf((h0 - mu) * r * lg[0] + lbeta[0], 0.f);
        y1 = fmaxf((h1 - mu) * r * lg[1] + lbeta[1], 0.f);
        id = N_TRACK + idl[t];
    }
    // wave-level segmented max scan (ids sorted within each domain; encodings disjoint)
    #pragma unroll
    for (int d = 1; d < 64; d <<= 1) {
        int oid = __shfl_down(id, d, 64);
        float o0 = __shfl_down(y0, d, 64);
        float o1 = __shfl_down(y1, d, 64);
        float o2 = __shfl_down(y2, d, 64);
        float o3 = __shfl_down(y3, d, 64);
        if (oid == id) {
            y0 = fmaxf(y0, o0); y1 = fmaxf(y1, o1);
            y2 = fmaxf(y2, o2); y3 = fmaxf(y3, o3);
        }
    }
    int pid = __shfl_up(id, 1, 64);
    bool head = (lane == 0) || (pid != id);
    if (id >= 0 && head) {
        if (id < N_TRACK) {
            unsigned int* p = (unsigned int*)&pool_t[(size_t)id * 4];
            atomicMax(p + 0, __float_as_uint(y0));
            atomicMax(p + 1, __float_as_uint(y1));
            atomicMax(p + 2, __float_as_uint(y2));
            atomicMax(p + 3, __float_as_uint(y3));
        } else {
            unsigned int* p = (unsigned int*)&pool_l[(size_t)(id - N_TRACK) * 2];
            atomicMax(p + 0, __float_as_uint(y0));
            atomicMax(p + 1, __float_as_uint(y1));
        }
    }
}

// ---------------- Node stage: pool -> feats(10) -> h(60) -> bf16-packed line; fused off[] ----------------
__global__ void node_kernel(const float* __restrict__ pool_t, const float* __restrict__ pool_l,
                            const float* __restrict__ tW, const float* __restrict__ tb,
                            const float* __restrict__ lW, const float* __restrict__ lb,
                            const float* __restrict__ fcW,
                            const int* __restrict__ att_dst,
                            unsigned int* __restrict__ hpack, int* __restrict__ off) {
    int i = blockIdx.x * blockDim.x + threadIdx.x;

    // fused per-dst edge offsets (att_dst sorted)
    if (i <= N_TRACK) {
        int lo = 0, hi = E_ATT;
        while (lo < hi) {
            int mid = (lo + hi) >> 1;
            if (att_dst[mid] < i) lo = mid + 1; else hi = mid;
        }
        off[i] = lo;
    }
    if (i >= N_ATT) return;

    float f[10];
    if (i < N_TRACK) {
        const float4 p = *(const float4*)(pool_t + (size_t)i * 4);
        #pragma unroll
        for (int j = 0; j < 10; j++)
            f[j] = p.x * tW[0*10+j] + p.y * tW[1*10+j] + p.z * tW[2*10+j] + p.w * tW[3*10+j] + tb[j];
    } else {
        const float2 p = *(const float2*)(pool_l + (size_t)(i - N_TRACK) * 2);
        #pragma unroll
        for (int j = 0; j < 10; j++)
            f[j] = p.x * lW[0*10+j] + p.y * lW[1*10+j] + lb[j];
    }

    unsigned int rec[REC_DW];
    #pragma unroll
    for (int hh = 0; hh < HEADS; hh++) {
        float a0 = 0.f, a1 = 0.f;
        #pragma unroll
        for (int k = 0; k < 10; k++) {
            a0 += f[k] * fcW[k * 60 + 2 * hh];
            a1 += f[k] * fcW[k * 60 + 2 * hh + 1];
        }
        unsigned int b0 = (unsigned int)__hip_bfloat16_raw(__float2bfloat16(a0)).x;
        unsigned int b1 = (unsigned int)__hip_bfloat16_raw(__float2bfloat16(a1)).x;
        rec[hh] = b0 | (b1 << 16);
    }
    rec[30] = 0u; rec[31] = 0u;

    uint4* rp = (uint4*)(hpack + (size_t)i * REC_DW);
    #pragma unroll
    for (int q = 0; q < 8; q++)
        rp[q] = make_uint4(rec[4*q], rec[4*q+1], rec[4*q+2], rec[4*q+3]);
}

// ---------------- Edge softmax + aggregate: 32 lanes per dst, lane = head ----------------
// One dword gather per edge per lane; el/er recomputed from bf16 h (2 FMAs).
__global__ void edge_kernel(const int* __restrict__ src, const int* __restrict__ off,
                            const unsigned int* __restrict__ hpack,
                            const float* __restrict__ attn_l, const float* __restrict__ attn_r,
                            const float* __restrict__ bias, float* __restrict__ out) {
    int grp = blockIdx.x * 8 + (threadIdx.x >> 5);
    int hh = threadIdx.x & 31;
    if (grp >= N_TRACK || hh >= HEADS) return;

    float al0 = attn_l[2 * hh], al1 = attn_l[2 * hh + 1];
    float ar0 = attn_r[2 * hh], ar1 = attn_r[2 * hh + 1];

    // er from own (dst) record
    unsigned int dd = hpack[(size_t)grp * REC_DW + hh];
    float hd0 = __uint_as_float(dd << 16);
    float hd1 = __uint_as_float(dd & 0xffff0000u);
    float er = hd0 * ar0 + hd1 * ar1;

    int s = off[grp], e = off[grp + 1];
    float m = -INFINITY, den = 0.f, n0 = 0.f, n1 = 0.f;

    for (int kk = s; kk < e; kk += 16) {
        int lim = e - kk;  // uniform per group
        int sv[16];
        #pragma unroll
        for (int j = 0; j < 16; j++) sv[j] = src[kk + (j < lim ? j : 0)];
        unsigned int d[16];
        #pragma unroll
        for (int j = 0; j < 16; j++) d[j] = hpack[(size_t)sv[j] * REC_DW + hh];
        #pragma unroll
        for (int j = 0; j < 16; j++) {
            if (j < lim) {
                float h0 = __uint_as_float(d[j] << 16);
                float h1 = __uint_as_float(d[j] & 0xffff0000u);
                float ev = h0 * al0 + h1 * al1 + er;
                ev = (ev > 0.f) ? ev : NEG_SLOPE * ev;
                float nm = fmaxf(m, ev);
                float sc = __expf(m - nm);   // first edge: exp(-inf) = 0
                float w  = __expf(ev - nm);
                den = den * sc + w;
                n0  = n0 * sc + w * h0;
                n1  = n1 * sc + w * h1;
                m = nm;
            }
        }
    }

    float o0 = 0.f, o1 = 0.f;
    if (den > 0.f) {
        float inv = 1.f / den;
        o0 = n0 * inv; o1 = n1 * inv;
    }
    ((float2*)out)[(size_t)grp * HEADS + hh] =
        make_float2(o0 + bias[2 * hh], o1 + bias[2 * hh + 1]);
}

extern "C" void kernel_launch(void* const* d_in, const int* in_sizes, int n_in,
                              void* d_out, int out_size, void* d_ws, size_t ws_size,
                              hipStream_t stream) {
    const float4* track_pts = (const float4*)d_in[0];
    const float2* lane_pts  = (const float2*)d_in[1];
    const int* pt_track_id  = (const int*)d_in[2];
    const int* pt_lane_id   = (const int*)d_in[3];
    const int* att_src      = (const int*)d_in[4];
    const int* att_dst      = (const int*)d_in[5];
    const float* track_mlp_W = (const float*)d_in[6];
    const float* track_mlp_b = (const float*)d_in[7];
    const float* track_ln_g  = (const float*)d_in[8];
    const float* track_ln_b  = (const float*)d_in[9];
    const float* track_out_W = (const float*)d_in[10];
    const float* track_out_b = (const float*)d_in[11];
    const float* lane_mlp_W  = (const float*)d_in[12];
    const float* lane_mlp_b  = (const float*)d_in[13];
    const float* lane_ln_g   = (const float*)d_in[14];
    const float* lane_ln_b   = (const float*)d_in[15];
    const float* lane_out_W  = (const float*)d_in[16];
    const float* lane_out_b  = (const float*)d_in[17];
    const float* gat_fc_W    = (const float*)d_in[18];
    const float* gat_attn_l  = (const float*)d_in[19];
    const float* gat_attn_r  = (const float*)d_in[20];
    const float* gat_bias    = (const float*)d_in[21];
    float* out = (float*)d_out;

    // workspace layout (hpack 128B-aligned: offsets are multiples of 128 B from d_ws)
    float* pool_t = (float*)d_ws;                        // 200000 floats
    float* pool_l = pool_t + 200000;                     // 100000 floats
    int*   off    = (int*)(pool_l + 100000);             // 50001 ints (pad to 50016)
    unsigned int* hpack = (unsigned int*)(off + 50016);  // 100000 * 32 dwords (12.8 MB)

    // zero the pools (ReLU outputs >= 0, empty segments -> 0)
    hipMemsetAsync(d_ws, 0, 300000 * sizeof(float), stream);

    point_kernel<<<(NP_T + NP_L + 255) / 256, 256, 0, stream>>>(
        track_pts, lane_pts, pt_track_id, pt_lane_id,
        track_mlp_W, track_mlp_b, track_ln_g, track_ln_b,
        lane_mlp_W, lane_mlp_b, lane_ln_g, lane_ln_b,
        pool_t, pool_l);
    node_kernel<<<(N_ATT + 255) / 256, 256, 0, stream>>>(
        pool_t, pool_l, track_out_W, track_out_b, lane_out_W, lane_out_b,
        gat_fc_W, att_dst, hpack, off);
    edge_kernel<<<(N_TRACK + 7) / 8, 256, 0, stream>>>(
        att_src, off, hpack, gat_attn_l, gat_attn_r, gat_bias, out);
}